// Round 1
// baseline (49.407 us; speedup 1.0000x reference)
//
#include <hip/hip_runtime.h>
#include <hip/hip_bf16.h>

// B=16, T=512, D=1024, E=8
// experts: (B,T,D,E) f32, gate: (B,T,E) f32, out: (B,T,D) f32
// out[b,t,d] = experts[b,t,d,argmax_e gate[b,t,e]]

#define D_DIM 1024
#define E_DIM 8

__global__ __launch_bounds__(256) void moe_select_kernel(
    const float* __restrict__ experts,
    const float* __restrict__ gate,
    float* __restrict__ out)
{
    const int bt = blockIdx.x;  // 0 .. B*T-1

    // Gate row is block-uniform -> scalar loads.
    const float* g = gate + (size_t)bt * E_DIM;
    float gv0 = g[0], gv1 = g[1], gv2 = g[2], gv3 = g[3];
    float gv4 = g[4], gv5 = g[5], gv6 = g[6], gv7 = g[7];

    // argmax with first-occurrence tie-break (matches jnp.argmax)
    int best = 0; float bv = gv0;
    if (gv1 > bv) { bv = gv1; best = 1; }
    if (gv2 > bv) { bv = gv2; best = 2; }
    if (gv3 > bv) { bv = gv3; best = 3; }
    if (gv4 > bv) { bv = gv4; best = 4; }
    if (gv5 > bv) { bv = gv5; best = 5; }
    if (gv6 > bv) { bv = gv6; best = 6; }
    if (gv7 > bv) { bv = gv7; best = 7; }

    const float* ex = experts + (size_t)bt * D_DIM * E_DIM + best;
    float* o = out + (size_t)bt * D_DIM;

    // 256 threads x 4 consecutive d each, float4 store.
    const int d0 = threadIdx.x * 4;
    float4 v;
    v.x = ex[(size_t)(d0 + 0) * E_DIM];
    v.y = ex[(size_t)(d0 + 1) * E_DIM];
    v.z = ex[(size_t)(d0 + 2) * E_DIM];
    v.w = ex[(size_t)(d0 + 3) * E_DIM];
    *reinterpret_cast<float4*>(o + d0) = v;
}

extern "C" void kernel_launch(void* const* d_in, const int* in_sizes, int n_in,
                              void* d_out, int out_size, void* d_ws, size_t ws_size,
                              hipStream_t stream) {
    const float* experts = (const float*)d_in[0];
    const float* gate    = (const float*)d_in[1];
    float* out = (float*)d_out;

    const int BT = 16 * 512;  // 8192 blocks
    moe_select_kernel<<<BT, 256, 0, stream>>>(experts, gate, out);
}